// Round 3
// baseline (308.181 us; speedup 1.0000x reference)
//
#include <hip/hip_runtime.h>
#include <hip/hip_bf16.h>

#define B_EV    8192
#define R_NEG   32
#define DIM     256
#define K_COM   5
#define M_ROWS  (B_EV * (R_NEG + 2))   // 278528
#define BM      64
#define N_NODES_C 100000

typedef _Float16 f16x8 __attribute__((ext_vector_type(8)));
typedef float    f32x4 __attribute__((ext_vector_type(4)));

// Single self-contained kernel. Per block of 64 event-rows:
//  1. gather node ids + gates (tid<64)
//  2. stage X = f16(state[node]*gate) tile [64][256] in XOR-swizzled LDS
//  3. K-loop (8 steps of K=32): stage W1 k-slab into LDS f16 transposed
//     ([col][kchunk] so B-fragments are single b128 reads), then 16 MFMA/wave
//  4. epilogue: relu(h+b1)@W2 partials, shfl reduce, cross-wave LDS reduce,
//     softmax(K=5), scatter to out.
__global__ __launch_bounds__(256, 2) void fused_kernel(
    const int* __restrict__ src, const int* __restrict__ dst,
    const int* __restrict__ neg, const float* __restrict__ ts,
    const float* __restrict__ state, const float* __restrict__ last_t,
    const float* __restrict__ log_decay,
    const float* __restrict__ W1, const float* __restrict__ b1,
    const float* __restrict__ W2, const float* __restrict__ b2,
    float* __restrict__ out)
{
    __shared__ f16x8 xt8[2048];            // 32 KB X tile [row][chunk^(row&7)]
    __shared__ f16x8 wt[256][4];           // 16 KB B slab [col][kc^(col&3)]
    __shared__ int   node_s[64];
    __shared__ float gate_s[64];
    __shared__ float part[4][64][K_COM];   // 5 KB cross-wave partials

    const int tid = threadIdx.x;
    const int m0  = blockIdx.x * BM;

    float ld    = log_decay[0];
    float decay = (ld > 30.f) ? ld : log1pf(expf(ld));   // stable softplus

    if (tid < 64) {
        int m  = m0 + tid;
        int be = m / 34;
        int sl = m - be * 34;
        int node = (sl == 0) ? src[be] : (sl == 1) ? dst[be] : neg[be * R_NEG + (sl - 2)];
        if ((unsigned)node >= (unsigned)N_NODES_C) node = 0;   // defensive clamp
        float dtv = fmaxf(ts[be] - last_t[node], 0.f);
        node_s[tid] = node;
        gate_s[tid] = expf(-decay * dtv);
    }
    __syncthreads();

    // Stage X tile: 64 rows x 256 cols f16, gate applied.
    {
        int c8 = tid & 31;        // 8-col chunk index
        int rb = tid >> 5;        // 0..7
        #pragma unroll
        for (int it = 0; it < 8; ++it) {
            int r = it * 8 + rb;
            int node = node_s[r];
            float gg = gate_s[r];
            const float* sp = state + (size_t)node * DIM + c8 * 8;
            float4 v0 = *(const float4*)(sp);
            float4 v1 = *(const float4*)(sp + 4);
            f16x8 pk;
            pk[0] = (_Float16)(v0.x * gg); pk[1] = (_Float16)(v0.y * gg);
            pk[2] = (_Float16)(v0.z * gg); pk[3] = (_Float16)(v0.w * gg);
            pk[4] = (_Float16)(v1.x * gg); pk[5] = (_Float16)(v1.y * gg);
            pk[6] = (_Float16)(v1.z * gg); pk[7] = (_Float16)(v1.w * gg);
            xt8[(r * 32 + c8) ^ (r & 7)] = pk;
        }
    }

    const int lane = tid & 63;
    const int w    = tid >> 6;      // wave 0..3, owns h-cols w*64..w*64+63
    const int l15  = lane & 15;
    const int g    = lane >> 4;
    const int bswz = g ^ (l15 & 3); // B-fragment kc swizzle (col&3 == l15&3)

    f32x4 acc[4][4];
    #pragma unroll
    for (int a = 0; a < 4; ++a)
        #pragma unroll
        for (int bb = 0; bb < 4; ++bb)
            acc[a][bb] = (f32x4){0.f, 0.f, 0.f, 0.f};

    for (int ks = 0; ks < 8; ++ks) {
        __syncthreads();   // prev wt reads done (and X-stage visible on ks=0)
        // Stage W1 k-slab [32][256] -> wt[col][kc] (transposed, f16).
        // For fixed (kc,j) the wave reads 64 consecutive floats of a W1 row
        // => coalesced 256B per load instruction.
        {
            const float* wp = W1 + (ks * 32) * 256 + tid;
            #pragma unroll
            for (int kc = 0; kc < 4; ++kc) {
                f16x8 pk;
                #pragma unroll
                for (int j = 0; j < 8; ++j)
                    pk[j] = (_Float16)wp[(kc * 8 + j) * 256];
                wt[tid][kc ^ (tid & 3)] = pk;
            }
        }
        __syncthreads();   // wt visible

        f16x8 av[4];
        #pragma unroll
        for (int mt = 0; mt < 4; ++mt) {
            int row = mt * 16 + l15;
            av[mt] = xt8[(row * 32 + ks * 4 + g) ^ (row & 7)];
        }
        #pragma unroll
        for (int nt = 0; nt < 4; ++nt) {
            f16x8 bv = wt[(w * 4 + nt) * 16 + l15][bswz];
            #pragma unroll
            for (int mt = 0; mt < 4; ++mt)
                acc[mt][nt] = __builtin_amdgcn_mfma_f32_16x16x32_f16(av[mt], bv, acc[mt][nt], 0, 0, 0);
        }
    }

    // Epilogue. C/D layout: col = lane&15, row = (lane>>4)*4 + reg (m89-verified).
    float b1v[4];
    float w2v[4][K_COM];
    #pragma unroll
    for (int nt = 0; nt < 4; ++nt) {
        int col = w * 64 + nt * 16 + l15;
        b1v[nt] = b1[col];
        #pragma unroll
        for (int k = 0; k < K_COM; ++k) w2v[nt][k] = W2[col * K_COM + k];
    }

    #pragma unroll
    for (int mt = 0; mt < 4; ++mt) {
        #pragma unroll
        for (int reg = 0; reg < 4; ++reg) {
            float p[K_COM] = {0.f, 0.f, 0.f, 0.f, 0.f};
            #pragma unroll
            for (int nt = 0; nt < 4; ++nt) {
                float h = fmaxf(acc[mt][nt][reg] + b1v[nt], 0.f);
                #pragma unroll
                for (int k = 0; k < K_COM; ++k) p[k] += h * w2v[nt][k];
            }
            #pragma unroll
            for (int off = 8; off >= 1; off >>= 1)
                #pragma unroll
                for (int k = 0; k < K_COM; ++k) p[k] += __shfl_xor(p[k], off);
            if (l15 == 0) {
                int row = mt * 16 + g * 4 + reg;
                #pragma unroll
                for (int k = 0; k < K_COM; ++k) part[w][row][k] = p[k];
            }
        }
    }
    __syncthreads();

    if (tid < 64) {
        float lg[K_COM];
        #pragma unroll
        for (int k = 0; k < K_COM; ++k)
            lg[k] = part[0][tid][k] + part[1][tid][k] + part[2][tid][k] + part[3][tid][k] + b2[k];
        float mx = lg[0];
        #pragma unroll
        for (int k = 1; k < K_COM; ++k) mx = fmaxf(mx, lg[k]);
        float sum = 0.f;
        #pragma unroll
        for (int k = 0; k < K_COM; ++k) { lg[k] = expf(lg[k] - mx); sum += lg[k]; }
        float inv = 1.f / sum;

        int m  = m0 + tid;
        int be = m / 34;
        int sl = m - be * 34;
        float* op;
        if (sl == 0)      op = out + (size_t)be * K_COM;
        else if (sl == 1) op = out + (size_t)B_EV * K_COM + (size_t)be * K_COM;
        else              op = out + (size_t)2 * B_EV * K_COM + ((size_t)be * R_NEG + (sl - 2)) * K_COM;
        #pragma unroll
        for (int k = 0; k < K_COM; ++k) op[k] = lg[k] * inv;
    }
}

extern "C" void kernel_launch(void* const* d_in, const int* in_sizes, int n_in,
                              void* d_out, int out_size, void* d_ws, size_t ws_size,
                              hipStream_t stream) {
    const int*   src       = (const int*)d_in[0];
    const int*   dst       = (const int*)d_in[1];
    const int*   neg       = (const int*)d_in[2];
    const float* ts        = (const float*)d_in[3];
    // d_in[4] = edge_idxs (unused by the reference)
    const float* state     = (const float*)d_in[5];
    const float* last_t    = (const float*)d_in[6];
    const float* log_decay = (const float*)d_in[7];
    const float* W1        = (const float*)d_in[8];
    const float* b1        = (const float*)d_in[9];
    const float* W2        = (const float*)d_in[10];
    const float* b2        = (const float*)d_in[11];

    fused_kernel<<<dim3(M_ROWS / BM), dim3(256), 0, stream>>>(
        src, dst, neg, ts, state, last_t, log_decay, W1, b1, W2, b2,
        (float*)d_out);
}